// Round 3
// baseline (500.254 us; speedup 1.0000x reference)
//
#include <hip/hip_runtime.h>
#include <stdint.h>

// VQVAE quantise, fp32 in/out.
// R3: occupancy fix — split S across 2 blocks (grid 512, 64-row dict tiles,
// LDS 72 KB -> 2 independent blocks/CU). Every per-iter stall (NT-store ack
// drain at __syncthreads vmcnt(0), load latency, barrier join skew) is now
// covered by the sibling block's work instead of idling the CU.
// Cross-block combine + one-hot 1.0 + cw gather move to a tiny finalize
// kernel; per-(btile,c) candidates are parked in the cw_out cells that the
// same finalize block later overwrites (kernel boundary = ordering).
// Tie-break exact: i0 in [0,2048), i1 in [2048,4096) => strict d1<d0 keeps
// global first-occurrence. Per-element distance math unchanged.

#define B_SZ 256
#define C_SZ 64
#define E_SZ 128
#define S_SZ 4096
#define CW   8192
#define TS   64    // s-rows per tile
#define LDB  136   // LDS B-row stride in f16

typedef __attribute__((ext_vector_type(4))) float    float4a;
typedef __attribute__((ext_vector_type(8))) _Float16 half8;

__device__ __forceinline__ void split8(float4a f0, float4a f1, half8& hi, half8& lo) {
    #pragma unroll
    for (int j = 0; j < 4; ++j) {
        _Float16 h0 = (_Float16)f0[j];
        hi[j]     = h0;
        lo[j]     = (_Float16)(f0[j] - (float)h0);
        _Float16 h1 = (_Float16)f1[j];
        hi[4 + j] = h1;
        lo[4 + j] = (_Float16)(f1[j] - (float)h1);
    }
}

// grid 512 = (shalf 0..1) x (btile 0..3) x (c 0..63), block 512 = 8 waves.
__global__ __launch_bounds__(512, 4) void argmin_mfma(
    const float* __restrict__ x,
    const float* __restrict__ dict,
    float* __restrict__ cw_out,
    float* __restrict__ oh)
{
    __shared__ __attribute__((aligned(16))) _Float16 bh[2][TS * LDB];  // 2x17 KB
    __shared__ __attribute__((aligned(16))) _Float16 bl[2][TS * LDB];  // 2x17 KB
    __shared__ float dsqp[2][TS][8];                                   // 4 KB
    // final reduction tables aliased onto staging LDS (used after the loop)
    float* rv = reinterpret_cast<float*>(bh);   // 64*64 floats = 16 KB
    int*   ri = reinterpret_cast<int*>(bl);     // 64*64 ints   = 16 KB

    const int tid   = threadIdx.x;
    const int lane  = tid & 63;
    const int quad  = lane >> 4;
    const int l15   = lane & 15;
    const int wid   = tid >> 6;
    const int mhalf = wid & 1;
    const int nquad = wid >> 1;
    const int c     = blockIdx.x & 63;
    const int btile = (blockIdx.x >> 6) & 3;
    const int shalf = blockIdx.x >> 8;
    const int sbase = shalf * 2048;

    // ---- runtime layout probes: true (row, col) of each (lane, reg) ----
    int m_attr[4], n_attr[4];
    {
        half8 ones, enc;
        #pragma unroll
        for (int j = 0; j < 8; ++j) { ones[j] = (_Float16)1.0f; enc[j] = (_Float16)(float)l15; }
        float4a z = {0.f, 0.f, 0.f, 0.f};
        float4a pr = __builtin_amdgcn_mfma_f32_16x16x32_f16(enc, ones, z, 0, 0, 0);
        float4a pc = __builtin_amdgcn_mfma_f32_16x16x32_f16(ones, enc, z, 0, 0, 0);
        #pragma unroll
        for (int r = 0; r < 4; ++r) {
            m_attr[r] = (int)(pr[r] * 0.03125f + 0.5f);   // row feeding this element
            n_attr[r] = (int)(pc[r] * 0.03125f + 0.5f);   // col feeding this element
        }
    }

    // ---- A fragments (regs, whole kernel): loader believes A[m=l15][k=kk*32+quad*8+j] ----
    half8 ah[2][4], al[2][4];
    #pragma unroll
    for (int mi = 0; mi < 2; ++mi) {
        int b = btile * 64 + mhalf * 32 + mi * 16 + l15;
        const float* xr = x + (size_t)b * CW + c * E_SZ;
        #pragma unroll
        for (int kk = 0; kk < 4; ++kk) {
            float4a f0 = *reinterpret_cast<const float4a*>(xr + kk * 32 + quad * 8);
            float4a f1 = *reinterpret_cast<const float4a*>(xr + kk * 32 + quad * 8 + 4);
            split8(f0, f1, ah[mi][kk], al[mi][kk]);
        }
    }

    // ---- staging coords (fixed per thread): 64 rows x 128 f32, 16 f32/thread ----
    const int srow = tid >> 3;
    const int kq   = (tid & 7) * 16;
    const float* drow = dict + ((size_t)c * S_SZ + sbase + srow) * E_SZ + kq;

    // ---- one-hot base for this block: rows (btile*64 + r, c), s in [sbase, sbase+2048) ----
    float* ohb = oh + ((size_t)(btile * 64) * C_SZ + c) * S_SZ + sbase;
    const size_t oh_bstride = (size_t)C_SZ * S_SZ;   // stride between consecutive b

    // ---- prologue: load + convert tile 0 into buffer 0 ----
    float4a pf[4];
    #pragma unroll
    for (int ck = 0; ck < 4; ++ck)
        pf[ck] = *reinterpret_cast<const float4a*>(drow + ck * 4);
    {
        float dp = 0.f;
        #pragma unroll
        for (int ck = 0; ck < 2; ++ck) {
            half8 h, l;
            split8(pf[2 * ck], pf[2 * ck + 1], h, l);
            #pragma unroll
            for (int j = 0; j < 4; ++j) {
                dp = fmaf(pf[2 * ck][j], pf[2 * ck][j], dp);
                dp = fmaf(pf[2 * ck + 1][j], pf[2 * ck + 1][j], dp);
            }
            *reinterpret_cast<half8*>(&bh[0][srow * LDB + kq + ck * 8]) = h;
            *reinterpret_cast<half8*>(&bl[0][srow * LDB + kq + ck * 8]) = l;
        }
        dsqp[0][srow][tid & 7] = dp;
    }

    float bestv[8];
    int   besti[8];
    #pragma unroll
    for (int i = 0; i < 8; ++i) { bestv[i] = 3.4e38f; besti[i] = 0; }

    __syncthreads();

    int cur = 0;
    for (int it = 0; it < 32; ++it) {
        // ---- issue next tile's global loads (latency hides under MFMA) ----
        if (it + 1 < 32) {
            const float* dr = drow + (size_t)(it + 1) * (TS * E_SZ);
            #pragma unroll
            for (int ck = 0; ck < 4; ++ck)
                pf[ck] = *reinterpret_cast<const float4a*>(dr + ck * 4);
        }

        // ---- zero 2 of this block's 64 half-rows (2048 floats each) ----
        {
            float4a zz = {0.f, 0.f, 0.f, 0.f};
            float* z0 = ohb + (size_t)(it * 2) * oh_bstride;
            float* z1 = z0 + oh_bstride;
            __builtin_nontemporal_store(zz, reinterpret_cast<float4a*>(z0) + tid);
            __builtin_nontemporal_store(zz, reinterpret_cast<float4a*>(z1) + tid);
        }

        // ---- MFMA phase on buf[cur] ----
        const _Float16* bhc = bh[cur];
        const _Float16* blc = bl[cur];
        float4a acc[2] = {{0.f,0.f,0.f,0.f},{0.f,0.f,0.f,0.f}};
        __builtin_amdgcn_s_setprio(1);
        #pragma unroll
        for (int kk = 0; kk < 4; ++kk) {
            const int sl = nquad * 16 + l15;   // loader believes col = l15
            half8 bhf = *reinterpret_cast<const half8*>(bhc + sl * LDB + kk * 32 + quad * 8);
            half8 blf = *reinterpret_cast<const half8*>(blc + sl * LDB + kk * 32 + quad * 8);
            #pragma unroll
            for (int mi = 0; mi < 2; ++mi) {
                acc[mi] = __builtin_amdgcn_mfma_f32_16x16x32_f16(
                    ah[mi][kk], bhf, acc[mi], 0, 0, 0);
                acc[mi] = __builtin_amdgcn_mfma_f32_16x16x32_f16(
                    ah[mi][kk], blf, acc[mi], 0, 0, 0);
                acc[mi] = __builtin_amdgcn_mfma_f32_16x16x32_f16(
                    al[mi][kk], bhf, acc[mi], 0, 0, 0);
            }
        }
        __builtin_amdgcn_s_setprio(0);

        // ---- epilogue: dist = d_sq - 2*cross (x_sq const per (b,c): argmin-invariant) ----
        #pragma unroll
        for (int r = 0; r < 4; ++r) {
            const int sl = nquad * 16 + n_attr[r];   // true col attribution
            float4a qa = *reinterpret_cast<const float4a*>(&dsqp[cur][sl][0]);
            float4a qb = *reinterpret_cast<const float4a*>(&dsqp[cur][sl][4]);
            float dsq = ((qa[0] + qa[1]) + (qa[2] + qa[3]))
                      + ((qb[0] + qb[1]) + (qb[2] + qb[3]));
            int sg = sbase + it * TS + sl;
            #pragma unroll
            for (int mi = 0; mi < 2; ++mi) {
                float dist = dsq - 2.0f * acc[mi][r];
                int slot = mi * 4 + r;
                if (dist < bestv[slot]) { bestv[slot] = dist; besti[slot] = sg; }
            }
        }

        // ---- convert prefetched tile into buf[cur^1] ----
        if (it + 1 < 32) {
            const int nb = cur ^ 1;
            float dp = 0.f;
            #pragma unroll
            for (int ck = 0; ck < 2; ++ck) {
                half8 h, l;
                split8(pf[2 * ck], pf[2 * ck + 1], h, l);
                #pragma unroll
                for (int j = 0; j < 4; ++j) {
                    dp = fmaf(pf[2 * ck][j], pf[2 * ck][j], dp);
                    dp = fmaf(pf[2 * ck + 1][j], pf[2 * ck + 1][j], dp);
                }
                *reinterpret_cast<half8*>(&bh[nb][srow * LDB + kq + ck * 8]) = h;
                *reinterpret_cast<half8*>(&bl[nb][srow * LDB + kq + ck * 8]) = l;
            }
            dsqp[nb][srow][tid & 7] = dp;
        }
        __syncthreads();
        cur ^= 1;
    }

    // loop-end barrier guarantees all LDS reads done; safe to alias rv/ri

    // ---- dump: bijective 64x64 scatter using true (row,col) attribution ----
    #pragma unroll
    for (int mi = 0; mi < 2; ++mi)
        #pragma unroll
        for (int r = 0; r < 4; ++r) {
            int row = mhalf * 32 + mi * 16 + m_attr[r];
            int col = nquad * 16 + n_attr[r];
            rv[row * 64 + col] = bestv[mi * 4 + r];
            ri[row * 64 + col] = besti[mi * 4 + r];
        }
    __syncthreads();

    if (tid < 64) {
        float bv = 3.4e38f; int bi = 0x7fffffff;
        for (int j = 0; j < 64; ++j) {
            float v = rv[tid * 64 + j];
            int   i = ri[tid * 64 + j];
            if (v < bv || (v == bv && i < bi)) { bv = v; bi = i; }  // first-occurrence tie
        }
        // park (dist, idx) candidate in the cw_out cell this (btile,c)'s
        // finalize block reads-then-overwrites. shalf slots are disjoint.
        float* cp = cw_out + (size_t)(btile * 64 + tid) * CW + c * E_SZ + shalf * 2;
        cp[0] = bv;
        cp[1] = __int_as_float(bi);
    }
}

// grid 256 = (btile, c), 256 threads: combine 2 candidates per row, write the
// one-hot 1.0, gather cw_embed (overwrites the candidate slab after reading).
__global__ __launch_bounds__(256) void finalize(
    const float* __restrict__ dict,
    float* __restrict__ cw_out,
    float* __restrict__ oh)
{
    __shared__ int fid[64];
    const int c     = blockIdx.x & 63;
    const int btile = blockIdx.x >> 6;
    const int tid   = threadIdx.x;

    if (tid < 64) {
        const float* cp = cw_out + (size_t)(btile * 64 + tid) * CW + c * E_SZ;
        float d0 = cp[0]; int i0 = __float_as_int(cp[1]);
        float d1 = cp[2]; int i1 = __float_as_int(cp[3]);
        // i0 < 2048 <= i1 always: strict d1<d0 preserves first-occurrence tie
        int bi = (d1 < d0) ? i1 : i0;
        fid[tid] = bi;
        oh[((size_t)(btile * 64 + tid) * C_SZ + c) * S_SZ + bi] = 1.0f;
    }
    __syncthreads();

    // gather: 64 rows x 32 float4, 4 threads/row x 8 float4 each
    const int row = tid >> 2, q = tid & 3;
    const int bi = fid[row];
    const float4a* src = reinterpret_cast<const float4a*>(
        dict + ((size_t)c * S_SZ + bi) * E_SZ) + q * 8;
    float4a* dst = reinterpret_cast<float4a*>(
        cw_out + (size_t)(btile * 64 + row) * CW + c * E_SZ) + q * 8;
    #pragma unroll
    for (int j = 0; j < 8; ++j) dst[j] = src[j];
}

extern "C" void kernel_launch(void* const* d_in, const int* in_sizes, int n_in,
                              void* d_out, int out_size, void* d_ws, size_t ws_size,
                              hipStream_t stream) {
    const float* x    = (const float*)d_in[0];
    const float* dict = (const float*)d_in[1];
    float* out = (float*)d_out;
    float* oh  = out + (size_t)B_SZ * CW;

    argmin_mfma<<<dim3(512), dim3(512), 0, stream>>>(x, dict, out, oh);
    finalize<<<dim3(256), dim3(256), 0, stream>>>(dict, out, oh);
}